// Round 4
// baseline (506.395 us; speedup 1.0000x reference)
//
#include <hip/hip_runtime.h>

#define BB 2048
#define AA 96
#define NIN 128
#define NHID 64
#define JC 4                // j-split: threads per atom
#define JW (NHID / JC)      // 16 hidden units per thread

// thread = (atom, jc). Grid = 768*JC blocks -> 12 blocks/CU -> 32 waves/CU.
// acc[16] per thread keeps the allocator honest (R3: it restructured at 64).
// W1 slice addresses are wave-uniform (jc per block) -> scalar loads, K$-resident.
__global__ __launch_bounds__(256, 8) void atomwise_kernel(
    const float* __restrict__ rep,
    const int*   __restrict__ zs,
    const float* __restrict__ mask,
    const float* __restrict__ w1,    // [NIN][NHID] row-major
    const float* __restrict__ b1,    // [NHID]
    const float* __restrict__ w2,    // [NHID]
    const float* __restrict__ b2,    // [1]
    const float* __restrict__ aref,  // [MAX_Z]
    const float* __restrict__ mean,  // [1]
    const float* __restrict__ stddev,// [1]
    float* __restrict__ out)         // [BB]
{
    const int jc    = blockIdx.x & (JC - 1);       // consecutive blocks share atoms -> L2 locality
    const int ab    = blockIdx.x >> 2;
    const int atom  = ab * 256 + threadIdx.x;
    const int jbase = jc * JW;

    const float* row = rep + (size_t)atom * NIN;
    const float* w1s = w1 + jbase;

    float acc[JW];
    #pragma unroll
    for (int j = 0; j < JW; ++j) acc[j] = b1[jbase + j];

    #pragma unroll 1
    for (int k = 0; k < NIN; k += 4) {
        const float4 rv = *reinterpret_cast<const float4*>(row + k);
        const float* wr = w1s + k * NHID;          // wave-uniform -> s_load_dwordx16
        #pragma unroll
        for (int j = 0; j < JW; ++j) {
            float a = acc[j];
            a = fmaf(rv.x, wr[j           ], a);
            a = fmaf(rv.y, wr[j +     NHID], a);
            a = fmaf(rv.z, wr[j + 2 * NHID], a);
            a = fmaf(rv.w, wr[j + 3 * NHID], a);
            acc[j] = a;
        }
    }

    const float LOG2E = 1.4426950408889634f;
    const float LN2   = 0.6931471805599453f;

    float dot = 0.0f;
    #pragma unroll
    for (int j = 0; j < JW; ++j) {
        float x  = acc[j];
        float ax = fabsf(x);
        float em = exp2f(-ax * LOG2E);                       // e^{-|x|}
        float sp = fmaxf(x, 0.0f) + log2f(1.0f + em) * LN2;  // softplus(x)
        dot = fmaf(sp - LN2, w2[jbase + j], dot);            // ssp = sp - log2
    }

    // partial yi for this jc; per-atom constants added once (jc==0, wave-uniform branch)
    float v = dot * stddev[0];
    if (jc == 0) v += fmaf(b2[0], stddev[0], mean[0]) + aref[zs[atom]];
    v *= mask[atom];

    // segmented wave reduction by molecule: a 64-lane wave of consecutive atoms
    // spans at most 2 molecules (AA=96 > 64) -> <=2 atomics per wave
    const int mol = atom / AA;
    const int m0  = __builtin_amdgcn_readfirstlane(mol);
    const int m1  = __shfl(mol, 63);
    float v0 = (mol == m0) ? v : 0.0f;
    float v1 = (mol == m0) ? 0.0f : v;
    #pragma unroll
    for (int off = 32; off; off >>= 1) {
        v0 += __shfl_xor(v0, off);
        v1 += __shfl_xor(v1, off);
    }
    if ((threadIdx.x & 63) == 0) {
        atomicAdd(out + m0, v0);
        if (m1 != m0) atomicAdd(out + m1, v1);
    }
}

extern "C" void kernel_launch(void* const* d_in, const int* in_sizes, int n_in,
                              void* d_out, int out_size, void* d_ws, size_t ws_size,
                              hipStream_t stream) {
    const float* rep    = (const float*)d_in[0];
    const int*   zs     = (const int*)  d_in[1];
    const float* mask   = (const float*)d_in[2];
    const float* w1     = (const float*)d_in[3];
    const float* b1     = (const float*)d_in[4];
    const float* w2     = (const float*)d_in[5];
    const float* b2     = (const float*)d_in[6];
    const float* aref   = (const float*)d_in[7];
    const float* mean   = (const float*)d_in[8];
    const float* stddev = (const float*)d_in[9];
    float* out = (float*)d_out;

    (void)hipMemsetAsync(out, 0, (size_t)out_size * sizeof(float), stream);

    const int atoms = BB * AA;                    // 196608
    const int blocks = (atoms / 256) * JC;        // 3072 = 12 per CU
    atomwise_kernel<<<dim3(blocks), dim3(256), 0, stream>>>(
        rep, zs, mask, w1, b1, w2, b2, aref, mean, stddev, out);
}

// Round 6
// 188.617 us; speedup vs baseline: 2.6848x; 2.6848x over previous
//
#include <hip/hip_runtime.h>

#define BB 2048
#define AA 96
#define NIN 128
#define NHID 64
#define MI 4                 // 16-atom M-tiles per wave

typedef __attribute__((ext_vector_type(8))) short bf16x8;
typedef __attribute__((ext_vector_type(4))) float f32x4;

// fp32 -> bf16 round-to-nearest-even, manual (avoids __hip_bfloat162
// bit_cast: not trivially copyable on this ROCm)
static __device__ __forceinline__ unsigned f2bf(float x) {
    unsigned u = __builtin_bit_cast(unsigned, x);
    return (u + 0x7FFFu + ((u >> 16) & 1u)) >> 16;
}
static __device__ __forceinline__ unsigned cvt_pk_bf16(float a, float b) {
    return f2bf(a) | (f2bf(b) << 16);
}

// wave = 16 atoms x 64 hid per M-tile, MI tiles per wave.
// B (W1 as bf16) lives entirely in VGPRs: 16 frags x 4 VGPR = 64 VGPRs.
// A-frag layout: m=lane&15, k=quad*8+j ; C layout: atom=quad*4+reg, hid=lane&15.
__global__ __launch_bounds__(256, 4) void atomwise_kernel(
    const float* __restrict__ rep,
    const int*   __restrict__ zs,
    const float* __restrict__ mask,
    const float* __restrict__ w1,    // [NIN][NHID]
    const float* __restrict__ b1,
    const float* __restrict__ w2,
    const float* __restrict__ b2,
    const float* __restrict__ aref,
    const float* __restrict__ mean,
    const float* __restrict__ stddev,
    float* __restrict__ out)
{
    const int lane = threadIdx.x & 63;
    const int wv   = threadIdx.x >> 6;
    const int nl   = lane & 15;
    const int quad = lane >> 4;
    const int wave_atom0 = (blockIdx.x * 4 + wv) * (16 * MI);

    // ---- preload W1 as B-frags bq[kstep][ntile]: B[k][n], n=nl+16t, k=32s+8*quad+j
    bf16x8 bq[4][4];
    #pragma unroll
    for (int s = 0; s < 4; ++s) {
        #pragma unroll
        for (int t = 0; t < 4; ++t) {
            union { bf16x8 v; unsigned u[4]; } fb;
            #pragma unroll
            for (int jp = 0; jp < 4; ++jp) {
                const int k = s * 32 + quad * 8 + jp * 2;
                const int n = t * 16 + nl;
                fb.u[jp] = cvt_pk_bf16(w1[k * NHID + n], w1[(k + 1) * NHID + n]);
            }
            bq[s][t] = fb.v;
        }
    }
    float b1v[4], w2v[4];
    #pragma unroll
    for (int t = 0; t < 4; ++t) { b1v[t] = b1[t * 16 + nl]; w2v[t] = w2[t * 16 + nl]; }
    const float sdv  = stddev[0];
    const float cadd = fmaf(b2[0], sdv, mean[0]);

    const float LOG2E = 1.4426950408889634f;
    const float LN2   = 0.6931471805599453f;

    #pragma unroll 1
    for (int mt = 0; mt < MI; ++mt) {
        const int atom0 = wave_atom0 + mt * 16;
        const float* rowp = rep + (size_t)(atom0 + nl) * NIN + quad * 8;

        float4 q[4][2];
        #pragma unroll
        for (int s = 0; s < 4; ++s) {
            q[s][0] = *reinterpret_cast<const float4*>(rowp + s * 32);
            q[s][1] = *reinterpret_cast<const float4*>(rowp + s * 32 + 4);
        }

        f32x4 acc[4];
        #pragma unroll
        for (int t = 0; t < 4; ++t) acc[t] = (f32x4){0.f, 0.f, 0.f, 0.f};

        #pragma unroll
        for (int s = 0; s < 4; ++s) {
            union { bf16x8 v; unsigned u[4]; } fa;
            fa.u[0] = cvt_pk_bf16(q[s][0].x, q[s][0].y);
            fa.u[1] = cvt_pk_bf16(q[s][0].z, q[s][0].w);
            fa.u[2] = cvt_pk_bf16(q[s][1].x, q[s][1].y);
            fa.u[3] = cvt_pk_bf16(q[s][1].z, q[s][1].w);
            #pragma unroll
            for (int t = 0; t < 4; ++t)
                acc[t] = __builtin_amdgcn_mfma_f32_16x16x32_bf16(fa.v, bq[s][t], acc[t], 0, 0, 0);
        }

        // epilogue: softplus, dot w2, reduce 16 lanes -> per-atom scalar
        float v[4];
        #pragma unroll
        for (int r = 0; r < 4; ++r) {
            float p = 0.f;
            #pragma unroll
            for (int t = 0; t < 4; ++t) {
                float x  = acc[t][r] + b1v[t];
                float ax = fabsf(x);
                float em = exp2f(-ax * LOG2E);
                float sp = fmaxf(x, 0.f) + log2f(1.f + em) * LN2;
                p = fmaf(sp - LN2, w2v[t], p);
            }
            p += __shfl_xor(p, 1); p += __shfl_xor(p, 2);
            p += __shfl_xor(p, 4); p += __shfl_xor(p, 8);
            v[r] = p;
        }
        if (nl == 0) {
            #pragma unroll
            for (int r = 0; r < 4; ++r) {
                const int ag = atom0 + quad * 4 + r;       // C row = quad*4+reg
                const float yi = fmaf(v[r], sdv, cadd) + aref[zs[ag]];
                atomicAdd(out + ag / AA, mask[ag] * yi);
            }
        }
    }
}

extern "C" void kernel_launch(void* const* d_in, const int* in_sizes, int n_in,
                              void* d_out, int out_size, void* d_ws, size_t ws_size,
                              hipStream_t stream) {
    const float* rep    = (const float*)d_in[0];
    const int*   zs     = (const int*)  d_in[1];
    const float* mask   = (const float*)d_in[2];
    const float* w1     = (const float*)d_in[3];
    const float* b1     = (const float*)d_in[4];
    const float* w2     = (const float*)d_in[5];
    const float* b2     = (const float*)d_in[6];
    const float* aref   = (const float*)d_in[7];
    const float* mean   = (const float*)d_in[8];
    const float* stddev = (const float*)d_in[9];
    float* out = (float*)d_out;

    (void)hipMemsetAsync(out, 0, (size_t)out_size * sizeof(float), stream);

    const int atoms  = BB * AA;                       // 196608
    const int blocks = atoms / (4 * 16 * MI);         // 768 -> 3 blocks/CU
    atomwise_kernel<<<dim3(blocks), dim3(256), 0, stream>>>(
        rep, zs, mask, w1, b1, w2, b2, aref, mean, stddev, out);
}

// Round 7
// 187.112 us; speedup vs baseline: 2.7064x; 1.0080x over previous
//
#include <hip/hip_runtime.h>

#define BB 2048
#define AA 96
#define NIN 128
#define NHID 64
#define MI 3                 // 16-atom M-tiles per wave; wave = 48 atoms
#define WST 136              // padded w1t row stride in bf16 elems (128+8)

typedef __attribute__((ext_vector_type(8))) short bf16x8;
typedef __attribute__((ext_vector_type(4))) float f32x4;

// fp32 -> bf16 RNE (manual; __hip_bfloat162 not trivially copyable here)
static __device__ __forceinline__ unsigned f2bf(float x) {
    unsigned u = __builtin_bit_cast(unsigned, x);
    return (u + 0x7FFFu + ((u >> 16) & 1u)) >> 16;
}
static __device__ __forceinline__ unsigned cvt_pk(float a, float b) {
    return f2bf(a) | (f2bf(b) << 16);
}

// wave = 16 atoms x 64 hid per tile via mfma_f32_16x16x32_bf16, MI tiles/wave.
// W1 lives in LDS (bf16, transposed, padded) -> ~100 VGPR, no spill (R6: 10MB spill).
// A-frag: m=nl, k=quad*8+j (per 32-k step). C: atom=quad*4+r, hid=nl (verified R6).
__global__ __launch_bounds__(256, 4) void atomwise_kernel(
    const float* __restrict__ rep,
    const int*   __restrict__ zs,
    const float* __restrict__ mask,
    const float* __restrict__ w1,    // [NIN][NHID] fp32
    const float* __restrict__ b1,
    const float* __restrict__ w2,
    const float* __restrict__ b2,
    const float* __restrict__ aref,
    const float* __restrict__ mean,
    const float* __restrict__ stddev,
    float* __restrict__ out)
{
    __shared__ unsigned short w1t[NHID * WST];   // 17408 B

    const int tid  = threadIdx.x;
    const int lane = tid & 63;
    const int wv   = tid >> 6;
    const int nl   = lane & 15;
    const int quad = lane >> 4;

    // ---- stage W1^T as bf16 into padded LDS (once per block)
    {
        const float4* w14 = (const float4*)w1;
        #pragma unroll
        for (int i = 0; i < 8; ++i) {
            const int    idx = tid + i * 256;     // float4 index in [0,2048)
            const float4 v   = w14[idx];
            const int e = idx * 4;                // element index; k=e>>6, n=e&63
            const int k = e >> 6, n = e & 63;
            w1t[(n    ) * WST + k] = (unsigned short)f2bf(v.x);
            w1t[(n + 1) * WST + k] = (unsigned short)f2bf(v.y);
            w1t[(n + 2) * WST + k] = (unsigned short)f2bf(v.z);
            w1t[(n + 3) * WST + k] = (unsigned short)f2bf(v.w);
        }
    }
    __syncthreads();

    float b1v[4], w2v[4];
    #pragma unroll
    for (int t = 0; t < 4; ++t) { b1v[t] = b1[t * 16 + nl]; w2v[t] = w2[t * 16 + nl]; }
    const float sdv  = stddev[0];
    const float cadd = fmaf(b2[0], sdv, mean[0]);

    const int wave_atom0 = (blockIdx.x * 4 + wv) * (16 * MI);

    const float LOG2E = 1.4426950408889634f;
    const float LN2   = 0.6931471805599453f;

    // prefetch tile 0's rep rows
    float4 q[8];
    {
        const float* rowp = rep + (size_t)(wave_atom0 + nl) * NIN + quad * 8;
        #pragma unroll
        for (int s = 0; s < 4; ++s) {
            q[2 * s]     = *(const float4*)(rowp + s * 32);
            q[2 * s + 1] = *(const float4*)(rowp + s * 32 + 4);
        }
    }

    #pragma unroll 1
    for (int mt = 0; mt < MI; ++mt) {
        const int atom0 = wave_atom0 + mt * 16;

        // consume q -> bf16 A-frags (waits on loads), then immediately
        // issue next tile's loads so they fly during MFMA+epilogue
        union { bf16x8 v; unsigned u[4]; } fa[4];
        #pragma unroll
        for (int s = 0; s < 4; ++s) {
            fa[s].u[0] = cvt_pk(q[2 * s].x,     q[2 * s].y);
            fa[s].u[1] = cvt_pk(q[2 * s].z,     q[2 * s].w);
            fa[s].u[2] = cvt_pk(q[2 * s + 1].x, q[2 * s + 1].y);
            fa[s].u[3] = cvt_pk(q[2 * s + 1].z, q[2 * s + 1].w);
        }
        if (mt + 1 < MI) {
            const float* rowp = rep + (size_t)(atom0 + 16 + nl) * NIN + quad * 8;
            #pragma unroll
            for (int s = 0; s < 4; ++s) {
                q[2 * s]     = *(const float4*)(rowp + s * 32);
                q[2 * s + 1] = *(const float4*)(rowp + s * 32 + 4);
            }
        }

        f32x4 acc[4];
        #pragma unroll
        for (int t = 0; t < 4; ++t) acc[t] = (f32x4){0.f, 0.f, 0.f, 0.f};

        #pragma unroll
        for (int s = 0; s < 4; ++s) {
            const int k0 = s * 32 + quad * 8;
            #pragma unroll
            for (int t = 0; t < 4; ++t) {
                const bf16x8 bf = *(const bf16x8*)&w1t[(t * 16 + nl) * WST + k0];
                acc[t] = __builtin_amdgcn_mfma_f32_16x16x32_bf16(fa[s].v, bf, acc[t], 0, 0, 0);
            }
        }

        // epilogue: softplus, dot w2, 16-lane reduce -> per-atom, then one atomic/tile
        float v[4];
        #pragma unroll
        for (int r = 0; r < 4; ++r) {
            float p = 0.f;
            #pragma unroll
            for (int t = 0; t < 4; ++t) {
                float x  = acc[t][r] + b1v[t];
                float ax = fabsf(x);
                float em = exp2f(-ax * LOG2E);
                float sp = fmaxf(x, 0.f) + log2f(1.f + em) * LN2;
                p = fmaf(sp - LN2, w2v[t], p);
            }
            p += __shfl_xor(p, 1); p += __shfl_xor(p, 2);
            p += __shfl_xor(p, 4); p += __shfl_xor(p, 8);
            v[r] = p;
        }
        if (nl == 0) {                            // lanes 0,16,32,48
            float ssum = 0.f;
            #pragma unroll
            for (int r = 0; r < 4; ++r) {
                const int ag = atom0 + quad * 4 + r;
                const float yi = fmaf(v[r], sdv, cadd) + aref[zs[ag]];
                ssum += mask[ag] * yi;
            }
            ssum += __shfl_xor(ssum, 16);
            ssum += __shfl_xor(ssum, 32);
            // 16 | 96: a tile never crosses a molecule boundary
            if (lane == 0) atomicAdd(out + atom0 / AA, ssum);
        }
    }
}

extern "C" void kernel_launch(void* const* d_in, const int* in_sizes, int n_in,
                              void* d_out, int out_size, void* d_ws, size_t ws_size,
                              hipStream_t stream) {
    const float* rep    = (const float*)d_in[0];
    const int*   zs     = (const int*)  d_in[1];
    const float* mask   = (const float*)d_in[2];
    const float* w1     = (const float*)d_in[3];
    const float* b1     = (const float*)d_in[4];
    const float* w2     = (const float*)d_in[5];
    const float* b2     = (const float*)d_in[6];
    const float* aref   = (const float*)d_in[7];
    const float* mean   = (const float*)d_in[8];
    const float* stddev = (const float*)d_in[9];
    float* out = (float*)d_out;

    (void)hipMemsetAsync(out, 0, (size_t)out_size * sizeof(float), stream);

    const int atoms  = BB * AA;                  // 196608
    const int blocks = atoms / (4 * 16 * MI);    // 1024 -> exactly 4 blocks/CU
    atomwise_kernel<<<dim3(blocks), dim3(256), 0, stream>>>(
        rep, zs, mask, w1, b1, w2, b2, aref, mean, stddev, out);
}

// Round 8
// 166.126 us; speedup vs baseline: 3.0483x; 1.1263x over previous
//
#include <hip/hip_runtime.h>

#define BB 2048
#define AA 96
#define NIN 128
#define NHID 64
#define MI 3                 // 16-atom tiles per wave

typedef __attribute__((ext_vector_type(8))) short bf16x8;
typedef __attribute__((ext_vector_type(4))) float f32x4;

// fp32 -> bf16 RNE (manual; __hip_bfloat162 not trivially copyable here)
static __device__ __forceinline__ unsigned f2bf(float x) {
    unsigned u = __builtin_bit_cast(unsigned, x);
    return (u + 0x7FFFu + ((u >> 16) & 1u)) >> 16;
}
static __device__ __forceinline__ unsigned cvt_pk(float a, float b) {
    return f2bf(a) | (f2bf(b) << 16);
}

// Design rule learned R2-R7: this compiler pins 64 VGPR/wave and spills the
// excess. So: per-s-step K loop (#pragma unroll 1) keeps live set ~45 regs;
// latency hiding via 8 waves/EU occupancy, not per-wave prefetch.
// LDS W1 frag image pre-swizzled [s][t][lane]*16B -> ds_read_b128 at
// base+lane*16: zero bank conflicts (R7 had 2.1M from 8-way aliasing).
// Layouts verified R6 (absmax 0.0625): A m=nl,k=quad*8+j; B n=nl,k=quad*8+j;
// C atom=quad*4+r, hid=nl.
__global__ __launch_bounds__(256) void atomwise_kernel(
    const float* __restrict__ rep,
    const int*   __restrict__ zs,
    const float* __restrict__ mask,
    const float* __restrict__ w1,    // [NIN][NHID] fp32
    const float* __restrict__ b1,
    const float* __restrict__ w2,
    const float* __restrict__ b2,
    const float* __restrict__ aref,
    const float* __restrict__ mean,
    const float* __restrict__ stddev,
    float* __restrict__ out)
{
    __shared__ bf16x8 w1f[1024];          // 16 KB frag image: [(s*4+t)*64 + lane]
    __shared__ float  b1s[NHID], w2s[NHID];

    const int tid  = threadIdx.x;
    const int lane = tid & 63;
    const int wv   = tid >> 6;
    const int nl   = lane & 15;
    const int quad = lane >> 4;

    // ---- stage W1 -> bf16 frag image (4 frags/thread, ds_write_b128 conflict-free)
    #pragma unroll
    for (int f = 0; f < 4; ++f) {
        const int fid = tid + f * 256;          // frag id 0..1023
        const int l2  = fid & 63;
        const int st  = fid >> 6;               // s*4 + t
        const int k0  = (st >> 2) * 32 + (l2 >> 4) * 8;
        const int n   = (st & 3) * 16 + (l2 & 15);
        union { bf16x8 v; unsigned u[4]; } fb;
        #pragma unroll
        for (int jp = 0; jp < 4; ++jp)
            fb.u[jp] = cvt_pk(w1[(k0 + 2 * jp) * NHID + n],
                              w1[(k0 + 2 * jp + 1) * NHID + n]);
        w1f[fid] = fb.v;
    }
    if (tid < NHID) { b1s[tid] = b1[tid]; w2s[tid] = w2[tid]; }
    __syncthreads();

    const float sdv  = stddev[0];
    const float cadd = fmaf(b2[0], sdv, mean[0]);
    const float LOG2E = 1.4426950408889634f;
    const float LN2   = 0.6931471805599453f;

    const int wid = blockIdx.x * 4 + wv;

    #pragma unroll 1
    for (int mt = 0; mt < MI; ++mt) {
        const int atom0 = (wid * MI + mt) * 16;
        const float* rowp = rep + (size_t)(atom0 + nl) * NIN + quad * 8;

        f32x4 acc[4];
        #pragma unroll
        for (int t = 0; t < 4; ++t) acc[t] = (f32x4){0.f, 0.f, 0.f, 0.f};

        #pragma unroll 1                       // keep live set small: 2 float4 in flight
        for (int s = 0; s < 4; ++s) {
            const float4 a0 = *(const float4*)(rowp + s * 32);
            const float4 a1 = *(const float4*)(rowp + s * 32 + 4);
            union { bf16x8 v; unsigned u[4]; } fa;
            fa.u[0] = cvt_pk(a0.x, a0.y);
            fa.u[1] = cvt_pk(a0.z, a0.w);
            fa.u[2] = cvt_pk(a1.x, a1.y);
            fa.u[3] = cvt_pk(a1.z, a1.w);
            const bf16x8* fr = &w1f[s * 256 + lane];   // (s*4+t)*64+lane, t stride 64
            #pragma unroll
            for (int t = 0; t < 4; ++t)
                acc[t] = __builtin_amdgcn_mfma_f32_16x16x32_bf16(fa.v, fr[t * 64], acc[t], 0, 0, 0);
        }

        // epilogue: softplus, dot w2, 16-lane reduce, 1 atomic per tile
        float v[4];
        #pragma unroll
        for (int r = 0; r < 4; ++r) {
            float p = 0.f;
            #pragma unroll
            for (int t = 0; t < 4; ++t) {
                float x  = acc[t][r] + b1s[t * 16 + nl];
                float ax = fabsf(x);
                float em = exp2f(-ax * LOG2E);
                float sp = fmaxf(x, 0.f) + log2f(1.f + em) * LN2;
                p = fmaf(sp - LN2, w2s[t * 16 + nl], p);
            }
            p += __shfl_xor(p, 1); p += __shfl_xor(p, 2);
            p += __shfl_xor(p, 4); p += __shfl_xor(p, 8);
            v[r] = p;
        }
        if (nl == 0) {                          // lanes 0,16,32,48 active
            float ssum = 0.f;
            #pragma unroll
            for (int r = 0; r < 4; ++r) {
                const int ag = atom0 + quad * 4 + r;
                const float yi = fmaf(v[r], sdv, cadd) + aref[zs[ag]];
                ssum += mask[ag] * yi;
            }
            ssum += __shfl_xor(ssum, 16);
            ssum += __shfl_xor(ssum, 32);
            if (lane == 0) atomicAdd(out + atom0 / AA, ssum);  // 16 | 96: no boundary crossing
        }
    }
}

extern "C" void kernel_launch(void* const* d_in, const int* in_sizes, int n_in,
                              void* d_out, int out_size, void* d_ws, size_t ws_size,
                              hipStream_t stream) {
    const float* rep    = (const float*)d_in[0];
    const int*   zs     = (const int*)  d_in[1];
    const float* mask   = (const float*)d_in[2];
    const float* w1     = (const float*)d_in[3];
    const float* b1     = (const float*)d_in[4];
    const float* w2     = (const float*)d_in[5];
    const float* b2     = (const float*)d_in[6];
    const float* aref   = (const float*)d_in[7];
    const float* mean   = (const float*)d_in[8];
    const float* stddev = (const float*)d_in[9];
    float* out = (float*)d_out;

    (void)hipMemsetAsync(out, 0, (size_t)out_size * sizeof(float), stream);

    const int atoms  = BB * AA;                  // 196608
    const int blocks = atoms / (4 * 16 * MI);    // 1024 blocks, 12288 waves = tiles/MI
    atomwise_kernel<<<dim3(blocks), dim3(256), 0, stream>>>(
        rep, zs, mask, w1, b1, w2, b2, aref, mean, stddev, out);
}